// Round 8
// baseline (2568.637 us; speedup 1.0000x reference)
//
#include <hip/hip_runtime.h>
#include <stdint.h>

#define BETA 0.9f

typedef unsigned short u16;
typedef unsigned char u8;
typedef _Float16 f16x8 __attribute__((ext_vector_type(8)));
typedef float f32x4 __attribute__((ext_vector_type(4)));

// async global->LDS, 16B per lane; lds ptr is wave-uniform base (+lane*16 by HW)
__device__ __forceinline__ void async_copy16(const void* g, void* l) {
  __builtin_amdgcn_global_load_lds(
      (const __attribute__((address_space(1))) uint32_t*)g,
      (__attribute__((address_space(3))) uint32_t*)l, 16, 0, 0);
}

// byte (8 spike bits) -> f16x8 with value bit * 2^-11 (f16 bits 0x1000)
__device__ __forceinline__ f16x8 expandB(uint32_t byte) {
  union { uint32_t u[4]; f16x8 v; } r;
  uint32_t z = byte | (byte << 15);  // bit 2m at 2m, bit 2m+1 at 2m+16
#pragma unroll
  for (int m = 0; m < 4; ++m)
    r.u[m] = ((z >> (2 * m)) & 0x10001u) << 12;
  return r.v;
}

// ---------------------------------------------------------------------------
// prep: fp16 2-split with scale folded into A (B always contributes 2^-11):
//   hi-part stores f16(f16(w)*2048)   [exact: power-of-2 shift]
//   mid-part stores f16((w-f16(w))*2048)
// Layout A[phys*2+part][ct][tap][co64][ci32]: each (virt,ct) block is a
// contiguous 12KB DMA unit (ct = 64-wide co-tile for block-level M split).
// Granule XOR-swizzle (g ^ ((co>>1)&3)) keeps LDS b128 reads conflict-free.
// Also transpose fc weights.
// ---------------------------------------------------------------------------
__global__ void prep_kernel(const float* __restrict__ W2, const float* __restrict__ W3,
                            const float* __restrict__ fw1, const float* __restrict__ fw2,
                            u16* __restrict__ A2c, u16* __restrict__ A3c,
                            float* __restrict__ fw1T, float* __restrict__ fw2T) {
  int o = blockIdx.x * 256 + threadIdx.x;
  if (o < 98304) {  // W2: (tap, co, ci), 3*128*256
    int tap = o >> 15, r = o & 32767, co = r >> 8, ci = r & 255;
    float w = W2[(co * 256 + ci) * 3 + tap];
    float h = (float)(_Float16)w;
    _Float16 hv = (_Float16)(h * 2048.0f);
    _Float16 mv = (_Float16)((w - h) * 2048.0f);
    u16 hb, mb;
    __builtin_memcpy(&hb, &hv, 2);
    __builtin_memcpy(&mb, &mv, 2);
    int c = ci >> 5, cl = ci & 31;
    int ct = co >> 6, col = co & 63;
    int g = ((cl >> 3) ^ ((co >> 1) & 3)) & 3;       // swizzled granule
    int pos = g * 8 + (cl & 7);
    // index = ((((c*2+part)*2 + ct)*3 + tap)*64 + col)*32 + pos
    A2c[((((c * 2 + 0) * 2 + ct) * 3 + tap) * 64 + col) * 32 + pos] = hb;
    A2c[((((c * 2 + 1) * 2 + ct) * 3 + tap) * 64 + col) * 32 + pos] = mb;
  }
  int o2 = o - 98304;  // W3: (tap, co, ci), 3*64*128 (NCT=1)
  if (o2 >= 0 && o2 < 24576) {
    int tap = o2 >> 13, r = o2 & 8191, co = r >> 7, ci = r & 127;
    float w = W3[(co * 128 + ci) * 3 + tap];
    float h = (float)(_Float16)w;
    _Float16 hv = (_Float16)(h * 2048.0f);
    _Float16 mv = (_Float16)((w - h) * 2048.0f);
    u16 hb, mb;
    __builtin_memcpy(&hb, &hv, 2);
    __builtin_memcpy(&mb, &mv, 2);
    int c = ci >> 5, cl = ci & 31;
    int g = ((cl >> 3) ^ ((co >> 1) & 3)) & 3;
    int pos = g * 8 + (cl & 7);
    A3c[(((c * 2 + 0) * 3 + tap) * 64 + co) * 32 + pos] = hb;
    A3c[(((c * 2 + 1) * 3 + tap) * 64 + co) * 32 + pos] = mb;
  }
  int o3 = o - (98304 + 24576);
  if (o3 >= 0 && o3 < 25600) {
    int f = o3 / 100, i = o3 % 100;
    fw1T[o3] = fw1[i * 256 + f];
  }
  int o4 = o - (98304 + 24576 + 25600);
  if (o4 >= 0 && o4 < 4000) {
    int i = o4 / 40, j = o4 % 40;
    fw2T[o4] = fw2[j * 100 + i];
  }
}

// ---------------------------------------------------------------------------
// conv1 (2->256, K=5, pad=2) + LIF1; writes byte-transposed spikes
// SBT2[b][l][g][t] (byte = spikes of co in [8g,8g+8), bit j = co 8g+j).
// ---------------------------------------------------------------------------
__global__ __launch_bounds__(256) void conv1_lif_kernel(
    const float* __restrict__ x, const float* __restrict__ W1,
    const float* __restrict__ b1, u8* __restrict__ SBT2) {
  __shared__ float xl[2][132];
  __shared__ u16 bl[8][128];
  int b = blockIdx.x, g = blockIdx.y;
  int tid = threadIdx.x;
  for (int i = tid; i < 264; i += 256) {
    int ci = i / 132, idx = i % 132, lg = idx - 2;
    xl[ci][idx] = (lg >= 0 && lg < 128) ? x[(b * 2 + ci) * 128 + lg] : 0.0f;
  }
  __syncthreads();
  int cosub = tid >> 5, tx = tid & 31;
  int co = g * 8 + cosub;
  float w[2][5];
#pragma unroll
  for (int ci = 0; ci < 2; ++ci)
#pragma unroll
    for (int k = 0; k < 5; ++k) w[ci][k] = W1[(co * 2 + ci) * 5 + k];
  float bias = b1[co];
  float cur[4];
#pragma unroll
  for (int j = 0; j < 4; ++j) {
    float acc = bias;
#pragma unroll
    for (int ci = 0; ci < 2; ++ci)
#pragma unroll
      for (int k = 0; k < 5; ++k) acc += w[ci][k] * xl[ci][4 * tx + j + k];
    cur[j] = acc;
  }
  float m[4] = {0.f, 0.f, 0.f, 0.f}, sp[4] = {0.f, 0.f, 0.f, 0.f};
  uint32_t bits[4] = {0u, 0u, 0u, 0u};
#pragma unroll
  for (int t = 0; t < 16; ++t) {
#pragma unroll
    for (int j = 0; j < 4; ++j) {
      m[j] = BETA * m[j] + cur[j] - sp[j];
      bool s = m[j] > 1.0f;
      bits[j] |= ((uint32_t)s) << t;
      sp[j] = s ? 1.0f : 0.0f;
    }
  }
#pragma unroll
  for (int j = 0; j < 4; ++j) bl[cosub][4 * tx + j] = (u16)bits[j];
  __syncthreads();
  if (tid < 128) {
    int l = tid;
    uint32_t wv[8];
#pragma unroll
    for (int j = 0; j < 8; ++j) wv[j] = bl[j][l];
    uint32_t ov[4];
#pragma unroll
    for (int k = 0; k < 4; ++k) {
      uint32_t v = 0;
#pragma unroll
      for (int tt = 0; tt < 4; ++tt) {
        int t = k * 4 + tt;
        uint32_t by = 0;
#pragma unroll
        for (int j = 0; j < 8; ++j) by |= ((wv[j] >> t) & 1u) << j;
        v |= by << (8 * tt);
      }
      ov[k] = v;
    }
    *(uint4*)(SBT2 + ((size_t)(b * 128 + l) * 32 + g) * 16) =
        make_uint4(ov[0], ov[1], ov[2], ov[3]);
  }
}

// ---------------------------------------------------------------------------
// MFMA conv (CIN->COUT, K=3, pad=1) + LIF.  [r7 structure + block M-split]
// Block tile: 64 co (blockIdx.z) x 8 l (blockIdx.y); 24KB LDS -> 6 blocks/CU
// for cross-block phase diversity (fills the matrix-pipe gaps left by the
// per-block barrier-aligned VALU head).
// A: async double-buffered LDS (12KB blocks), one barrier per part.
// B: byte loads + in-register expansion, one-chunk-ahead prefetch.
// Waves 2x2 (wy: 32-co half, wx: 4-l half); MT=2, acc=32 VGPR.
// ---------------------------------------------------------------------------
template <int CIN, int COUT, bool SBTOUT>
__global__ __launch_bounds__(256, 6) void conv_mfma_kernel(
    const u8* __restrict__ SBT, const u16* __restrict__ Agc,
    const float* __restrict__ bias, void* __restrict__ outp) {
  constexpr int NPHYS = CIN / 32;
  constexpr int NVIRT = 2 * NPHYS;
  constexpr int NCT = COUT / 64;
  constexpr int MT = 2;                    // m-tiles per wave (of 16)
  constexpr int GB = CIN / 8;
  constexpr int ABYTES = 3 * 64 * 32 * 2;  // 12288 per (virt,ct) A block
  constexpr int AW = ABYTES / 4;
  constexpr int AISS = AW / 1024;
  __shared__ __align__(16) char lds[2 * ABYTES];  // 24576; epilogue needs 20480

  int b = blockIdx.x, lb = blockIdx.y * 8, ct = blockIdx.z;
  int tid = threadIdx.x, lane = tid & 63, wid = tid >> 6;
  int wx = wid & 1, wy = wid >> 1;
  int q = lane >> 4, xx = lane & 15;
  int mloc = wy * 32;                      // co_local base for this wave
  int lw = lb + wx * 4;
  int qs8 = (q ^ ((xx >> 1) & 3)) * 8;     // swizzled granule offset (u16)

  f32x4 acc[MT][4];
#pragma unroll
  for (int mt = 0; mt < MT; ++mt)
#pragma unroll
    for (int nt = 0; nt < 4; ++nt) acc[mt][nt] = (f32x4){0.f, 0.f, 0.f, 0.f};

  // prologue: bytes for phys chunk 0, async copy for virtual part 0
  uint32_t byt[6];
#pragma unroll
  for (int u = 0; u < 6; ++u) {
    int l_in = lw + u - 1;
    byt[u] = ((unsigned)l_in < 128u)
                 ? (uint32_t)SBT[((size_t)(b * 128 + l_in) * GB + q) * 16 + xx]
                 : 0u;
  }
  {
    const char* gsrc = (const char*)Agc + (size_t)ct * ABYTES +
                       (size_t)wid * AW + lane * 16;
    char* ldst = lds + wid * AW;
#pragma unroll
    for (int i = 0; i < AISS; ++i) async_copy16(gsrc + i * 1024, ldst + i * 1024);
  }

  f16x8 Bf[6];
#pragma unroll 2
  for (int v = 0; v < NVIRT; ++v) {
    __syncthreads();  // drains copy v (issued one full part earlier)
    if (v + 1 < NVIRT) {
      const char* gsrc = (const char*)Agc + ((size_t)(v + 1) * NCT + ct) * ABYTES +
                         (size_t)wid * AW + lane * 16;
      char* ldst = lds + ((v + 1) & 1) * ABYTES + wid * AW;
#pragma unroll
      for (int i = 0; i < AISS; ++i) async_copy16(gsrc + i * 1024, ldst + i * 1024);
    }
    if ((v & 1) == 0) {
#pragma unroll
      for (int u = 0; u < 6; ++u) Bf[u] = expandB(byt[u]);
      int pn = (v >> 1) + 1;
      if (pn < NPHYS) {
#pragma unroll
        for (int u = 0; u < 6; ++u) {
          int l_in = lw + u - 1;
          byt[u] = ((unsigned)l_in < 128u)
                       ? (uint32_t)SBT[((size_t)(b * 128 + l_in) * GB + pn * 4 + q) * 16 + xx]
                       : 0u;
        }
      }
    }
    const u16* Asv = (const u16*)(lds + (v & 1) * ABYTES);
#pragma unroll
    for (int tap = 0; tap < 3; ++tap)
#pragma unroll
      for (int mt = 0; mt < MT; ++mt) {
        f16x8 Af = *(const f16x8*)(Asv + ((size_t)(tap * 64 + mloc + mt * 16 + xx)) * 32 + qs8);
#pragma unroll
        for (int nt = 0; nt < 4; ++nt)
          acc[mt][nt] = __builtin_amdgcn_mfma_f32_16x16x32_f16(
              Af, Bf[nt + tap], acc[mt][nt], 0, 0, 0);
      }
  }
  __syncthreads();

  // epilogue: per-wave scr transpose (stride 19, <=2-way) -> LIF -> bl
  float* scr = (float*)(void*)lds + wid * 1216;  // 64 rows x 19 words
  u16* bl = (u16*)(lds + 19456);                 // [64 co_local][8 l_local]
#pragma unroll
  for (int mt = 0; mt < MT; ++mt) {
#pragma unroll
    for (int nt = 0; nt < 4; ++nt)
#pragma unroll
      for (int r = 0; r < 4; ++r)
        scr[(nt * 16 + q * 4 + r) * 19 + xx] = acc[mt][nt][r];
    __syncthreads();
    int col = mloc + mt * 16 + xx;
    float bc = bias[ct * 64 + col];
    const float* rowp = scr + (q * 16 + xx) * 19;
    float mm = 0.f, sp = 0.f;
    uint32_t bits = 0;
#pragma unroll
    for (int t = 0; t < 16; ++t) {
      float cur = rowp[t] + bc;
      mm = BETA * mm + cur - sp;
      bool s = mm > 1.0f;
      bits |= ((uint32_t)s) << t;
      sp = s ? 1.0f : 0.0f;
    }
    bl[col * 8 + wx * 4 + q] = (u16)bits;
    __syncthreads();
  }

  if constexpr (SBTOUT) {
    constexpr int GBo = COUT / 8;   // full-row granule count
    if (tid < 64) {                 // 8 g_local x 8 l
      int g = tid & 7, ll = tid >> 3;
      uint32_t wv[8];
#pragma unroll
      for (int j = 0; j < 8; ++j) wv[j] = bl[(8 * g + j) * 8 + ll];
      uint32_t ov[4];
#pragma unroll
      for (int k = 0; k < 4; ++k) {
        uint32_t v = 0;
#pragma unroll
        for (int tt = 0; tt < 4; ++tt) {
          int t = k * 4 + tt;
          uint32_t by = 0;
#pragma unroll
          for (int j = 0; j < 8; ++j) by |= ((wv[j] >> t) & 1u) << j;
          v |= by << (8 * tt);
        }
        ov[k] = v;
      }
      *(uint4*)((u8*)outp + ((size_t)(b * 128 + lb + ll) * GBo + ct * 8 + g) * 16) =
          make_uint4(ov[0], ov[1], ov[2], ov[3]);
    }
  } else {
    if (tid < 64) {
      uint4 v = *(const uint4*)(bl + tid * 8);
      *(uint4*)((u16*)outp + ((size_t)b * COUT + ct * 64 + tid) * 128 + lb) = v;
    }
  }
}

// ---------------------------------------------------------------------------
// head: conv4 (64->2) + LIF4, fc1 (256->100) + LIF5, fc2 accumulated (popcount)
// ---------------------------------------------------------------------------
__global__ __launch_bounds__(256) void head_kernel(
    const u16* __restrict__ s3bits, const float* __restrict__ W4,
    const float* __restrict__ b4, const float* __restrict__ fw1T,
    const float* __restrict__ fb1, const float* __restrict__ fw2T,
    const float* __restrict__ fb2, float* __restrict__ out) {
  __shared__ u16 s3l[64][130];
  __shared__ float W4l[384];
  __shared__ u16 flat4[256];
  __shared__ u16 s5b[100];
  int b = blockIdx.x, tid = threadIdx.x;

  for (int i = tid; i < 64 * 130; i += 256) {
    int ci = i / 130, idx = i % 130, lg = idx - 1;
    s3l[ci][idx] = (lg >= 0 && lg < 128) ? s3bits[((size_t)b * 64 + ci) * 128 + lg] : (u16)0;
  }
  for (int i = tid; i < 384; i += 256) W4l[i] = W4[i];
  __syncthreads();

  {
    int co = tid >> 7, l = tid & 127;
    float acc4[16];
#pragma unroll
    for (int t = 0; t < 16; ++t) acc4[t] = 0.f;
    for (int ci = 0; ci < 64; ++ci) {
#pragma unroll
      for (int k = 0; k < 3; ++k) {
        float wv = W4l[(co * 64 + ci) * 3 + k];
        uint32_t msk = s3l[ci][l + k];
#pragma unroll
        for (int t = 0; t < 16; ++t)
          acc4[t] = fmaf(wv, (float)((msk >> t) & 1u), acc4[t]);
      }
    }
    float bc = b4[co];
    float m = 0.f, sp = 0.f;
    uint32_t bits = 0;
#pragma unroll
    for (int t = 0; t < 16; ++t) {
      m = BETA * m + (acc4[t] + bc) - sp;
      bool s = m > 1.0f;
      bits |= ((uint32_t)s) << t;
      sp = s ? 1.0f : 0.0f;
    }
    flat4[tid] = (u16)bits;
  }
  __syncthreads();

  if (tid < 100) {
    float acc5[16];
#pragma unroll
    for (int t = 0; t < 16; ++t) acc5[t] = 0.f;
    for (int f = 0; f < 256; ++f) {
      float wv = fw1T[f * 100 + tid];
      uint32_t msk = flat4[f];
#pragma unroll
      for (int t = 0; t < 16; ++t)
        acc5[t] = fmaf(wv, (float)((msk >> t) & 1u), acc5[t]);
    }
    float bc = fb1[tid];
    float m = 0.f, sp = 0.f;
    uint32_t bits = 0;
#pragma unroll
    for (int t = 0; t < 16; ++t) {
      m = BETA * m + (acc5[t] + bc) - sp;
      bool s = m > 1.0f;
      bits |= ((uint32_t)s) << t;
      sp = s ? 1.0f : 0.0f;
    }
    s5b[tid] = (u16)bits;
  }
  __syncthreads();

  if (tid < 40) {
    float a = 0.f;
    for (int i = 0; i < 100; ++i) {
      float wv = fw2T[i * 40 + tid];
      a = fmaf(wv, (float)__popc((uint32_t)s5b[i]), a);
    }
    out[b * 40 + tid] = a * 0.0625f + fb2[tid];
  }
}

// ---------------------------------------------------------------------------
extern "C" void kernel_launch(void* const* d_in, const int* in_sizes, int n_in,
                              void* d_out, int out_size, void* d_ws, size_t ws_size,
                              hipStream_t stream) {
  const float* x   = (const float*)d_in[0];
  const float* W1  = (const float*)d_in[1];
  const float* b1  = (const float*)d_in[2];
  const float* W2  = (const float*)d_in[3];
  const float* b2  = (const float*)d_in[4];
  const float* W3  = (const float*)d_in[5];
  const float* b3  = (const float*)d_in[6];
  const float* W4  = (const float*)d_in[7];
  const float* b4  = (const float*)d_in[8];
  const float* fw1 = (const float*)d_in[9];
  const float* fb1 = (const float*)d_in[10];
  const float* fw2 = (const float*)d_in[11];
  const float* fb2 = (const float*)d_in[12];
  float* out = (float*)d_out;

  char* ws = (char*)d_ws;
  u16*   A2c  = (u16*)(ws);                       // 393216 B [virt][ct][tap][co64][ci32]
  u16*   A3c  = (u16*)(ws + 393216);              //  98304 B
  float* fw1T = (float*)(ws + 491520);            // 102400 B
  float* fw2T = (float*)(ws + 593920);            //  16000 B (pad to 610304)
  u8*    SBT2 = (u8*)(ws + 610304);               // 134217728 B [b][l][32][16]
  u8*    SBT3 = (u8*)(ws + 610304 + 134217728);   //  67108864 B [b][l][16][16]
  u16*   s3b  = (u16*)(ws + 610304 + 134217728 + 67108864);  // 33554432 B u16 [b][co][l]
  // total: 235,491,328 B

  prep_kernel<<<dim3(596), dim3(256), 0, stream>>>(W2, W3, fw1, fw2, A2c, A3c, fw1T, fw2T);
  conv1_lif_kernel<<<dim3(2048, 32), dim3(256), 0, stream>>>(x, W1, b1, SBT2);
  conv_mfma_kernel<256, 128, true><<<dim3(2048, 16, 2), dim3(256), 0, stream>>>(SBT2, A2c, b2, SBT3);
  conv_mfma_kernel<128, 64, false><<<dim3(2048, 16, 1), dim3(256), 0, stream>>>(SBT3, A3c, b3, s3b);
  head_kernel<<<dim3(2048), dim3(256), 0, stream>>>(s3b, W4, b4, fw1T, fb1, fw2T, fb2, out);
}

// Round 9
// 1938.366 us; speedup vs baseline: 1.3252x; 1.3252x over previous
//
#include <hip/hip_runtime.h>
#include <stdint.h>

#define BETA 0.9f

typedef unsigned short u16;
typedef unsigned char u8;
typedef _Float16 f16x8 __attribute__((ext_vector_type(8)));
typedef float f32x4 __attribute__((ext_vector_type(4)));

// async global->LDS, 16B per lane; lds ptr is wave-uniform base (+lane*16 by HW)
__device__ __forceinline__ void async_copy16(const void* g, void* l) {
  __builtin_amdgcn_global_load_lds(
      (const __attribute__((address_space(1))) uint32_t*)g,
      (__attribute__((address_space(3))) uint32_t*)l, 16, 0, 0);
}

// byte (8 spike bits) -> f16x8 with value bit * 2^-11 (f16 bits 0x1000)
__device__ __forceinline__ f16x8 expandB(uint32_t byte) {
  union { uint32_t u[4]; f16x8 v; } r;
  uint32_t z = byte | (byte << 15);  // bit 2m at 2m, bit 2m+1 at 2m+16
#pragma unroll
  for (int m = 0; m < 4; ++m)
    r.u[m] = ((z >> (2 * m)) & 0x10001u) << 12;
  return r.v;
}

// ---------------------------------------------------------------------------
// prep: fp16 2-split with scale folded into A (B always contributes 2^-11):
//   hi-part stores f16(f16(w)*2048)   [exact: power-of-2 shift]
//   mid-part stores f16((w-f16(w))*2048)
// Layout A[virt][ct][tap][co64][ci32]: each (virt,ct) block is a contiguous
// 12KB DMA unit (ct = 64-wide co-tile for block-level M split).
// Granule XOR-swizzle (g ^ ((co>>1)&3)) keeps LDS b128 reads conflict-free.
// Also transpose fc weights.
// ---------------------------------------------------------------------------
__global__ void prep_kernel(const float* __restrict__ W2, const float* __restrict__ W3,
                            const float* __restrict__ fw1, const float* __restrict__ fw2,
                            u16* __restrict__ A2c, u16* __restrict__ A3c,
                            float* __restrict__ fw1T, float* __restrict__ fw2T) {
  int o = blockIdx.x * 256 + threadIdx.x;
  if (o < 98304) {  // W2: (tap, co, ci), 3*128*256
    int tap = o >> 15, r = o & 32767, co = r >> 8, ci = r & 255;
    float w = W2[(co * 256 + ci) * 3 + tap];
    float h = (float)(_Float16)w;
    _Float16 hv = (_Float16)(h * 2048.0f);
    _Float16 mv = (_Float16)((w - h) * 2048.0f);
    u16 hb, mb;
    __builtin_memcpy(&hb, &hv, 2);
    __builtin_memcpy(&mb, &mv, 2);
    int c = ci >> 5, cl = ci & 31;
    int ct = co >> 6, col = co & 63;
    int g = ((cl >> 3) ^ ((co >> 1) & 3)) & 3;       // swizzled granule
    int pos = g * 8 + (cl & 7);
    A2c[((((c * 2 + 0) * 2 + ct) * 3 + tap) * 64 + col) * 32 + pos] = hb;
    A2c[((((c * 2 + 1) * 2 + ct) * 3 + tap) * 64 + col) * 32 + pos] = mb;
  }
  int o2 = o - 98304;  // W3: (tap, co, ci), 3*64*128 (NCT=1)
  if (o2 >= 0 && o2 < 24576) {
    int tap = o2 >> 13, r = o2 & 8191, co = r >> 7, ci = r & 127;
    float w = W3[(co * 128 + ci) * 3 + tap];
    float h = (float)(_Float16)w;
    _Float16 hv = (_Float16)(h * 2048.0f);
    _Float16 mv = (_Float16)((w - h) * 2048.0f);
    u16 hb, mb;
    __builtin_memcpy(&hb, &hv, 2);
    __builtin_memcpy(&mb, &mv, 2);
    int c = ci >> 5, cl = ci & 31;
    int g = ((cl >> 3) ^ ((co >> 1) & 3)) & 3;
    int pos = g * 8 + (cl & 7);
    A3c[(((c * 2 + 0) * 3 + tap) * 64 + co) * 32 + pos] = hb;
    A3c[(((c * 2 + 1) * 3 + tap) * 64 + co) * 32 + pos] = mb;
  }
  int o3 = o - (98304 + 24576);
  if (o3 >= 0 && o3 < 25600) {
    int f = o3 / 100, i = o3 % 100;
    fw1T[o3] = fw1[i * 256 + f];
  }
  int o4 = o - (98304 + 24576 + 25600);
  if (o4 >= 0 && o4 < 4000) {
    int i = o4 / 40, j = o4 % 40;
    fw2T[o4] = fw2[j * 100 + i];
  }
}

// ---------------------------------------------------------------------------
// conv1 (2->256, K=5, pad=2) + LIF1; writes byte-transposed spikes
// SBT2[b][l][g][t] (byte = spikes of co in [8g,8g+8), bit j = co 8g+j).
// ---------------------------------------------------------------------------
__global__ __launch_bounds__(256) void conv1_lif_kernel(
    const float* __restrict__ x, const float* __restrict__ W1,
    const float* __restrict__ b1, u8* __restrict__ SBT2) {
  __shared__ float xl[2][132];
  __shared__ u16 bl[8][128];
  int b = blockIdx.x, g = blockIdx.y;
  int tid = threadIdx.x;
  for (int i = tid; i < 264; i += 256) {
    int ci = i / 132, idx = i % 132, lg = idx - 2;
    xl[ci][idx] = (lg >= 0 && lg < 128) ? x[(b * 2 + ci) * 128 + lg] : 0.0f;
  }
  __syncthreads();
  int cosub = tid >> 5, tx = tid & 31;
  int co = g * 8 + cosub;
  float w[2][5];
#pragma unroll
  for (int ci = 0; ci < 2; ++ci)
#pragma unroll
    for (int k = 0; k < 5; ++k) w[ci][k] = W1[(co * 2 + ci) * 5 + k];
  float bias = b1[co];
  float cur[4];
#pragma unroll
  for (int j = 0; j < 4; ++j) {
    float acc = bias;
#pragma unroll
    for (int ci = 0; ci < 2; ++ci)
#pragma unroll
      for (int k = 0; k < 5; ++k) acc += w[ci][k] * xl[ci][4 * tx + j + k];
    cur[j] = acc;
  }
  float m[4] = {0.f, 0.f, 0.f, 0.f}, sp[4] = {0.f, 0.f, 0.f, 0.f};
  uint32_t bits[4] = {0u, 0u, 0u, 0u};
#pragma unroll
  for (int t = 0; t < 16; ++t) {
#pragma unroll
    for (int j = 0; j < 4; ++j) {
      m[j] = BETA * m[j] + cur[j] - sp[j];
      bool s = m[j] > 1.0f;
      bits[j] |= ((uint32_t)s) << t;
      sp[j] = s ? 1.0f : 0.0f;
    }
  }
#pragma unroll
  for (int j = 0; j < 4; ++j) bl[cosub][4 * tx + j] = (u16)bits[j];
  __syncthreads();
  if (tid < 128) {
    int l = tid;
    uint32_t wv[8];
#pragma unroll
    for (int j = 0; j < 8; ++j) wv[j] = bl[j][l];
    uint32_t ov[4];
#pragma unroll
    for (int k = 0; k < 4; ++k) {
      uint32_t v = 0;
#pragma unroll
      for (int tt = 0; tt < 4; ++tt) {
        int t = k * 4 + tt;
        uint32_t by = 0;
#pragma unroll
        for (int j = 0; j < 8; ++j) by |= ((wv[j] >> t) & 1u) << j;
        v |= by << (8 * tt);
      }
      ov[k] = v;
    }
    *(uint4*)(SBT2 + ((size_t)(b * 128 + l) * 32 + g) * 16) =
        make_uint4(ov[0], ov[1], ov[2], ov[3]);
  }
}

// ---------------------------------------------------------------------------
// MFMA conv (CIN->COUT, K=3, pad=1) + LIF.  [r7 occupancy + wide-N wave tile]
// Block tile: 64 co (blockIdx.z) x 16 l (blockIdx.y); waves 2x2
// (wy: 32-co half -> MT=2, wx: 8-l half -> NT=8). Per v: 6 ds_read_b128
// (halved vs r7), 48 MFMA, AISS=3 DMA. acc 64 AGPR; ~100 VGPR; (256,3).
// A: async double-buffered LDS (12KB blocks), one barrier per part.
// B: byte loads + in-register expansion, one-chunk-ahead prefetch.
// ---------------------------------------------------------------------------
template <int CIN, int COUT, bool SBTOUT>
__global__ __launch_bounds__(256, 3) void conv_mfma_kernel(
    const u8* __restrict__ SBT, const u16* __restrict__ Agc,
    const float* __restrict__ bias, void* __restrict__ outp) {
  constexpr int NPHYS = CIN / 32;
  constexpr int NVIRT = 2 * NPHYS;
  constexpr int NCT = COUT / 64;
  constexpr int MT = 2;                    // 16-co tiles per wave
  constexpr int NT = 8;                    // l-positions per wave
  constexpr int GB = CIN / 8;
  constexpr int ABYTES = 3 * 64 * 32 * 2;  // 12288 per (virt,ct) A block
  constexpr int AW = ABYTES / 4;
  constexpr int AISS = AW / 1024;          // 3
  __shared__ __align__(16) char lds[2 * ABYTES];  // 24576; epilogue needs 21504

  int b = blockIdx.x, lb = blockIdx.y * 16, ct = blockIdx.z;
  int tid = threadIdx.x, lane = tid & 63, wid = tid >> 6;
  int wx = wid & 1, wy = wid >> 1;
  int q = lane >> 4, xx = lane & 15;
  int mloc = wy * 32;                      // co_local base for this wave
  int lw = lb + wx * 8;
  int qs8 = (q ^ ((xx >> 1) & 3)) * 8;     // swizzled granule offset (u16)

  f32x4 acc[MT][NT];
#pragma unroll
  for (int mt = 0; mt < MT; ++mt)
#pragma unroll
    for (int nt = 0; nt < NT; ++nt) acc[mt][nt] = (f32x4){0.f, 0.f, 0.f, 0.f};

  // prologue: bytes for phys chunk 0, async copy for virtual part 0
  uint32_t byt[10];
#pragma unroll
  for (int u = 0; u < 10; ++u) {
    int l_in = lw + u - 1;
    byt[u] = ((unsigned)l_in < 128u)
                 ? (uint32_t)SBT[((size_t)(b * 128 + l_in) * GB + q) * 16 + xx]
                 : 0u;
  }
  {
    const char* gsrc = (const char*)Agc + (size_t)ct * ABYTES +
                       (size_t)wid * AW + lane * 16;
    char* ldst = lds + wid * AW;
#pragma unroll
    for (int i = 0; i < AISS; ++i) async_copy16(gsrc + i * 1024, ldst + i * 1024);
  }

  f16x8 Bf[10];
#pragma unroll 2
  for (int v = 0; v < NVIRT; ++v) {
    __syncthreads();  // drains copy v (issued one full part earlier)
    if (v + 1 < NVIRT) {
      const char* gsrc = (const char*)Agc + ((size_t)(v + 1) * NCT + ct) * ABYTES +
                         (size_t)wid * AW + lane * 16;
      char* ldst = lds + ((v + 1) & 1) * ABYTES + wid * AW;
#pragma unroll
      for (int i = 0; i < AISS; ++i) async_copy16(gsrc + i * 1024, ldst + i * 1024);
    }
    if ((v & 1) == 0) {
#pragma unroll
      for (int u = 0; u < 10; ++u) Bf[u] = expandB(byt[u]);
      int pn = (v >> 1) + 1;
      if (pn < NPHYS) {
#pragma unroll
        for (int u = 0; u < 10; ++u) {
          int l_in = lw + u - 1;
          byt[u] = ((unsigned)l_in < 128u)
                       ? (uint32_t)SBT[((size_t)(b * 128 + l_in) * GB + pn * 4 + q) * 16 + xx]
                       : 0u;
        }
      }
    }
    const u16* Asv = (const u16*)(lds + (v & 1) * ABYTES);
#pragma unroll
    for (int tap = 0; tap < 3; ++tap)
#pragma unroll
      for (int mt = 0; mt < MT; ++mt) {
        f16x8 Af = *(const f16x8*)(Asv + ((size_t)(tap * 64 + mloc + mt * 16 + xx)) * 32 + qs8);
#pragma unroll
        for (int nt = 0; nt < NT; ++nt)
          acc[mt][nt] = __builtin_amdgcn_mfma_f32_16x16x32_f16(
              Af, Bf[nt + tap], acc[mt][nt], 0, 0, 0);
      }
  }
  __syncthreads();

  // epilogue: per-wave scr transpose (stride 19, <=2-way), 4 nt-tiles per
  // pass (2 passes per mt) -> LIF -> bl
  float* scr = (float*)(void*)lds + wid * 1216;  // 64 rows x 19 words
  u16* bl = (u16*)(lds + 19456);                 // [64 co_local][16 l_local]
#pragma unroll
  for (int mt = 0; mt < MT; ++mt) {
#pragma unroll
    for (int h = 0; h < 2; ++h) {
#pragma unroll
      for (int u2 = 0; u2 < 4; ++u2)
#pragma unroll
        for (int r = 0; r < 4; ++r)
          scr[(u2 * 16 + q * 4 + r) * 19 + xx] = acc[mt][h * 4 + u2][r];
      __syncthreads();
      int col = mloc + mt * 16 + xx;
      float bc = bias[ct * 64 + col];
      const float* rowp = scr + (q * 16 + xx) * 19;
      float mm = 0.f, sp = 0.f;
      uint32_t bits = 0;
#pragma unroll
      for (int t = 0; t < 16; ++t) {
        float cur = rowp[t] + bc;
        mm = BETA * mm + cur - sp;
        bool s = mm > 1.0f;
        bits |= ((uint32_t)s) << t;
        sp = s ? 1.0f : 0.0f;
      }
      bl[col * 16 + wx * 8 + h * 4 + q] = (u16)bits;
      __syncthreads();
    }
  }

  if constexpr (SBTOUT) {
    constexpr int GBo = COUT / 8;   // full-row granule count
    if (tid < 128) {                // 8 g_local x 16 l
      int g = tid & 7, ll = tid >> 3;
      uint32_t wv[8];
#pragma unroll
      for (int j = 0; j < 8; ++j) wv[j] = bl[(8 * g + j) * 16 + ll];
      uint32_t ov[4];
#pragma unroll
      for (int k = 0; k < 4; ++k) {
        uint32_t v = 0;
#pragma unroll
        for (int tt = 0; tt < 4; ++tt) {
          int t = k * 4 + tt;
          uint32_t by = 0;
#pragma unroll
          for (int j = 0; j < 8; ++j) by |= ((wv[j] >> t) & 1u) << j;
          v |= by << (8 * tt);
        }
        ov[k] = v;
      }
      *(uint4*)((u8*)outp + ((size_t)(b * 128 + lb + ll) * GBo + ct * 8 + g) * 16) =
          make_uint4(ov[0], ov[1], ov[2], ov[3]);
    }
  } else {
    if (tid < 128) {  // 64 co x 2 halves of 8 l (16B each)
      int col = tid >> 1, hf = tid & 1;
      uint4 v = *(const uint4*)(bl + col * 16 + hf * 8);
      *(uint4*)((u16*)outp + ((size_t)b * COUT + ct * 64 + col) * 128 + lb + hf * 8) = v;
    }
  }
}

// ---------------------------------------------------------------------------
// head: conv4 (64->2) + LIF4, fc1 (256->100) + LIF5, fc2 accumulated (popcount)
// ---------------------------------------------------------------------------
__global__ __launch_bounds__(256) void head_kernel(
    const u16* __restrict__ s3bits, const float* __restrict__ W4,
    const float* __restrict__ b4, const float* __restrict__ fw1T,
    const float* __restrict__ fb1, const float* __restrict__ fw2T,
    const float* __restrict__ fb2, float* __restrict__ out) {
  __shared__ u16 s3l[64][130];
  __shared__ float W4l[384];
  __shared__ u16 flat4[256];
  __shared__ u16 s5b[100];
  int b = blockIdx.x, tid = threadIdx.x;

  for (int i = tid; i < 64 * 130; i += 256) {
    int ci = i / 130, idx = i % 130, lg = idx - 1;
    s3l[ci][idx] = (lg >= 0 && lg < 128) ? s3bits[((size_t)b * 64 + ci) * 128 + lg] : (u16)0;
  }
  for (int i = tid; i < 384; i += 256) W4l[i] = W4[i];
  __syncthreads();

  {
    int co = tid >> 7, l = tid & 127;
    float acc4[16];
#pragma unroll
    for (int t = 0; t < 16; ++t) acc4[t] = 0.f;
    for (int ci = 0; ci < 64; ++ci) {
#pragma unroll
      for (int k = 0; k < 3; ++k) {
        float wv = W4l[(co * 64 + ci) * 3 + k];
        uint32_t msk = s3l[ci][l + k];
#pragma unroll
        for (int t = 0; t < 16; ++t)
          acc4[t] = fmaf(wv, (float)((msk >> t) & 1u), acc4[t]);
      }
    }
    float bc = b4[co];
    float m = 0.f, sp = 0.f;
    uint32_t bits = 0;
#pragma unroll
    for (int t = 0; t < 16; ++t) {
      m = BETA * m + (acc4[t] + bc) - sp;
      bool s = m > 1.0f;
      bits |= ((uint32_t)s) << t;
      sp = s ? 1.0f : 0.0f;
    }
    flat4[tid] = (u16)bits;
  }
  __syncthreads();

  if (tid < 100) {
    float acc5[16];
#pragma unroll
    for (int t = 0; t < 16; ++t) acc5[t] = 0.f;
    for (int f = 0; f < 256; ++f) {
      float wv = fw1T[f * 100 + tid];
      uint32_t msk = flat4[f];
#pragma unroll
      for (int t = 0; t < 16; ++t)
        acc5[t] = fmaf(wv, (float)((msk >> t) & 1u), acc5[t]);
    }
    float bc = fb1[tid];
    float m = 0.f, sp = 0.f;
    uint32_t bits = 0;
#pragma unroll
    for (int t = 0; t < 16; ++t) {
      m = BETA * m + (acc5[t] + bc) - sp;
      bool s = m > 1.0f;
      bits |= ((uint32_t)s) << t;
      sp = s ? 1.0f : 0.0f;
    }
    s5b[tid] = (u16)bits;
  }
  __syncthreads();

  if (tid < 40) {
    float a = 0.f;
    for (int i = 0; i < 100; ++i) {
      float wv = fw2T[i * 40 + tid];
      a = fmaf(wv, (float)__popc((uint32_t)s5b[i]), a);
    }
    out[b * 40 + tid] = a * 0.0625f + fb2[tid];
  }
}

// ---------------------------------------------------------------------------
extern "C" void kernel_launch(void* const* d_in, const int* in_sizes, int n_in,
                              void* d_out, int out_size, void* d_ws, size_t ws_size,
                              hipStream_t stream) {
  const float* x   = (const float*)d_in[0];
  const float* W1  = (const float*)d_in[1];
  const float* b1  = (const float*)d_in[2];
  const float* W2  = (const float*)d_in[3];
  const float* b2  = (const float*)d_in[4];
  const float* W3  = (const float*)d_in[5];
  const float* b3  = (const float*)d_in[6];
  const float* W4  = (const float*)d_in[7];
  const float* b4  = (const float*)d_in[8];
  const float* fw1 = (const float*)d_in[9];
  const float* fb1 = (const float*)d_in[10];
  const float* fw2 = (const float*)d_in[11];
  const float* fb2 = (const float*)d_in[12];
  float* out = (float*)d_out;

  char* ws = (char*)d_ws;
  u16*   A2c  = (u16*)(ws);                       // 393216 B [virt][ct][tap][co64][ci32]
  u16*   A3c  = (u16*)(ws + 393216);              //  98304 B
  float* fw1T = (float*)(ws + 491520);            // 102400 B
  float* fw2T = (float*)(ws + 593920);            //  16000 B (pad to 610304)
  u8*    SBT2 = (u8*)(ws + 610304);               // 134217728 B [b][l][32][16]
  u8*    SBT3 = (u8*)(ws + 610304 + 134217728);   //  67108864 B [b][l][16][16]
  u16*   s3b  = (u16*)(ws + 610304 + 134217728 + 67108864);  // 33554432 B u16 [b][co][l]
  // total: 235,491,328 B

  prep_kernel<<<dim3(596), dim3(256), 0, stream>>>(W2, W3, fw1, fw2, A2c, A3c, fw1T, fw2T);
  conv1_lif_kernel<<<dim3(2048, 32), dim3(256), 0, stream>>>(x, W1, b1, SBT2);
  conv_mfma_kernel<256, 128, true><<<dim3(2048, 8, 2), dim3(256), 0, stream>>>(SBT2, A2c, b2, SBT3);
  conv_mfma_kernel<128, 64, false><<<dim3(2048, 8, 1), dim3(256), 0, stream>>>(SBT3, A3c, b3, s3b);
  head_kernel<<<dim3(2048), dim3(256), 0, stream>>>(s3b, W4, b4, fw1T, fb1, fw2T, fb2, out);
}